// Round 1
// baseline (830.781 us; speedup 1.0000x reference)
//
#include <hip/hip_runtime.h>
#include <cstdint>

typedef __attribute__((ext_vector_type(8))) short bf16x8;
typedef __attribute__((ext_vector_type(4))) float f32x4;

#define B_ 2
#define S_ 2048
#define ENC_ 2048
#define HID_ 2048
#define HQ_ 8
#define HKV_ 4
#define D_ 256
#define L_ 4096

__device__ __forceinline__ short f2bf(float f) {
  uint32_t u = __builtin_bit_cast(uint32_t, f);
  u = (u + 0x7fffu + ((u >> 16) & 1u)) >> 16;
  return (short)u;
}
__device__ __forceinline__ float bf2f(short s) {
  uint32_t u = ((uint32_t)(uint16_t)s) << 16;
  return __builtin_bit_cast(float, u);
}

// global -> LDS direct copy, 16B per lane. LDS dest = wave-uniform base + lane*16.
__device__ __forceinline__ void llds16(const void* g, void* s) {
  __builtin_amdgcn_global_load_lds(
      (const __attribute__((address_space(1))) void*)(__builtin_bit_cast(uintptr_t, g)),
      (__attribute__((address_space(3))) void*)(uint32_t)(__builtin_bit_cast(uintptr_t, s)),
      16, 0, 0);
}

// ---------------- fp32 -> bf16 convert ----------------
__global__ __launch_bounds__(256) void cvt_f32_bf16(const float* __restrict__ in,
                                                    short* __restrict__ out, int n) {
  int i = (blockIdx.x * 256 + threadIdx.x) * 4;
  if (i >= n) return;
  float4 v = *(const float4*)(in + i);
  short4 r;
  r.x = f2bf(v.x); r.y = f2bf(v.y); r.z = f2bf(v.z); r.w = f2bf(v.w);
  *(short4*)(out + i) = r;
}

// ---------------- GEMM C = A * B^T (both K-major), 128x128 tile, BK=32 ----------------
template <int BF16OUT>
__global__ __launch_bounds__(256, 2)
void gemm_bt(const short* __restrict__ A, const short* __restrict__ Bw,
             void* __restrict__ Cout, int M, int N, int K) {
  __shared__ __align__(16) short As[128 * 32];
  __shared__ __align__(16) short Bs[128 * 32];
  const int t = threadIdx.x;
  const int w = t >> 6;
  const int l = t & 63;
  const int lr = l & 15;
  const int lq = l >> 4;
  const int bm = blockIdx.y * 128;
  const int bn = blockIdx.x * 128;
  const int wm = (w & 1) * 64;
  const int wn = (w >> 1) * 64;

  f32x4 acc[4][4];
#pragma unroll
  for (int i = 0; i < 4; i++)
#pragma unroll
    for (int j = 0; j < 4; j++) acc[i][j] = f32x4{0.f, 0.f, 0.f, 0.f};

  const int srow = 32 * w + (l >> 2);  // staging row (issue 0); +16 for issue 1
  const int scol = (l & 3) * 8;
  const short* gA = A + (size_t)(bm + srow) * K + scol;
  const short* gB = Bw + (size_t)(bn + srow) * K + scol;
  short* sA = &As[srow * 32 + scol];
  short* sB = &Bs[srow * 32 + scol];

  for (int k0 = 0; k0 < K; k0 += 32) {
    llds16(gA + k0, sA);
    llds16(gA + k0 + (size_t)16 * K, sA + 16 * 32);
    llds16(gB + k0, sB);
    llds16(gB + k0 + (size_t)16 * K, sB + 16 * 32);
    __syncthreads();
    bf16x8 af[4], bfr[4];
#pragma unroll
    for (int mi = 0; mi < 4; mi++)
      af[mi] = *(const bf16x8*)&As[(wm + 16 * mi + lr) * 32 + lq * 8];
#pragma unroll
    for (int ni = 0; ni < 4; ni++)
      bfr[ni] = *(const bf16x8*)&Bs[(wn + 16 * ni + lr) * 32 + lq * 8];
    __syncthreads();
#pragma unroll
    for (int mi = 0; mi < 4; mi++)
#pragma unroll
      for (int ni = 0; ni < 4; ni++)
        acc[mi][ni] =
            __builtin_amdgcn_mfma_f32_16x16x32_bf16(af[mi], bfr[ni], acc[mi][ni], 0, 0, 0);
  }

#pragma unroll
  for (int mi = 0; mi < 4; mi++)
#pragma unroll
    for (int ni = 0; ni < 4; ni++)
#pragma unroll
      for (int r = 0; r < 4; r++) {
        int row = bm + wm + 16 * mi + lq * 4 + r;  // C layout: row=(l>>4)*4+reg
        int col = bn + wn + 16 * ni + lr;          //           col=l&15
        float v = acc[mi][ni][r];
        if (BF16OUT)
          ((short*)Cout)[(size_t)row * N + col] = f2bf(v);
        else
          ((float*)Cout)[(size_t)row * N + col] = v;
      }
}

// ---------------- RMSNorm (+ optional RoPE) + head-major scatter ----------------
__global__ __launch_bounds__(256)
void norm_rope(const short* __restrict__ src, int src_ld, int col0, int H,
               short* __restrict__ dst, int dstL, int pos_off, int do_rope,
               const float* __restrict__ wn, const float* __restrict__ cosp,
               const float* __restrict__ sinp) {
  __shared__ float sh[256];
  __shared__ float red[4];
  int bid = blockIdx.x;
  int s = bid & (S_ - 1);
  int h = (bid >> 11) % H;
  int b = (bid >> 11) / H;
  int d = threadIdx.x;
  int w = d >> 6, l = d & 63;
  float x = bf2f(src[(size_t)(b * S_ + s) * src_ld + col0 + h * D_ + d]);
  float ss = x * x;
#pragma unroll
  for (int off = 32; off; off >>= 1) ss += __shfl_xor(ss, off, 64);
  if (l == 0) red[w] = ss;
  __syncthreads();
  float tot = red[0] + red[1] + red[2] + red[3];
  float y = x * rsqrtf(tot * (1.0f / D_) + 1e-6f) * (1.0f + wn[d]);
  float outv = y;
  if (do_rope) {
    sh[d] = y;
    __syncthreads();
    float c = cosp[s * D_ + d];
    float sn = sinp[s * D_ + d];
    outv = (d < 128) ? (y * c - sh[d + 128] * sn) : (y * c + sh[d - 128] * sn);
  }
  dst[((size_t)(b * H + h) * dstL + pos_off + s) * D_ + d] = f2bf(outv);
}

// ---------------- V transpose: (token, d) -> Vt[b][h][d][l] ----------------
__global__ __launch_bounds__(256)
void v_transpose(const short* __restrict__ qkv_self, const short* __restrict__ kv_cross,
                 short* __restrict__ Vt) {
  __shared__ __align__(16) short tile[64][72];
  int bid = blockIdx.x;  // b(2) h(4) lt(64) dt(4)
  int dt = bid & 3;
  int lt = (bid >> 2) & 63;
  int h = (bid >> 8) & 3;
  int b = bid >> 10;
  int t = threadIdx.x;
  int rl = t >> 2;
  int cc = (t & 3) * 16;
  int l = lt * 64 + rl;
  const short* src;
  if (lt < 32)
    src = qkv_self + (size_t)(b * S_ + l) * 4096 + 3072 + h * D_ + dt * 64 + cc;
  else
    src = kv_cross + (size_t)(b * ENC_ + (l - S_)) * 2048 + 1024 + h * D_ + dt * 64 + cc;
  *(bf16x8*)&tile[rl][cc] = *(const bf16x8*)src;
  *(bf16x8*)&tile[rl][cc + 8] = *(const bf16x8*)(src + 8);
  __syncthreads();
  int dl = t >> 2;
  int lc = (t & 3) * 16;
  bf16x8 v0, v1;
#pragma unroll
  for (int j = 0; j < 8; j++) {
    v0[j] = tile[lc + j][dl];
    v1[j] = tile[lc + 8 + j][dl];
  }
  short* dstp = Vt + ((size_t)(b * HKV_ + h) * D_ + dt * 64 + dl) * (size_t)L_ + lt * 64 + lc;
  *(bf16x8*)dstp = v0;
  *(bf16x8*)(dstp + 8) = v1;
}

// ---------------- Flash attention with tanh softcap ----------------
__global__ __launch_bounds__(256, 2)
void flash_attn(const short* __restrict__ Q, const short* __restrict__ K,
                const short* __restrict__ Vt, short* __restrict__ attn_out) {
  __shared__ __align__(16) short KV[256 * 72];  // union: K view [64][264], Vt view [256][72]
  __shared__ __align__(16) short Ps[64 * 72];
  int t = threadIdx.x, w = t >> 6, l = t & 63;
  int lr = l & 15, lq = l >> 4;
  int bid = blockIdx.x;
  int qt = 31 - (bid & 31);  // heavy q-tiles first
  int h = (bid >> 5) & 7;
  int b = bid >> 8;
  int hk = h >> 1;  // GQA repeat=2
  int q0 = qt * 64;

  bf16x8 qf[8];  // wave's 16 q-rows, full D=256, A-fragment layout, kept in regs
  {
    const short* qb = Q + ((size_t)(b * HQ_ + h) * S_ + q0 + 16 * w + lr) * D_ + lq * 8;
#pragma unroll
    for (int kf = 0; kf < 8; kf++) qf[kf] = *(const bf16x8*)(qb + kf * 32);
  }
  f32x4 o[16];
#pragma unroll
  for (int i = 0; i < 16; i++) o[i] = f32x4{0.f, 0.f, 0.f, 0.f};
  float m_i[4] = {-1e9f, -1e9f, -1e9f, -1e9f};
  float l_i[4] = {0.f, 0.f, 0.f, 0.f};

  const size_t kbase = (size_t)(b * HKV_ + hk) * L_ * D_;
  const size_t vbase = (size_t)(b * HKV_ + hk) * (size_t)D_ * L_;

  int nself = q0 >> 6;
  int niter = nself + 1 + 32;
  for (int it = 0; it < niter; ++it) {
    int kt = (it <= nself) ? it : (32 + (it - nself - 1));
    int k0 = kt * 64;
    bool diag = (it == nself);

    // stage K tile (64 keys x 256 d) -> KV as [64][264]
    {
      int krow = t >> 2;
      int kc = (t & 3) * 8;
      const short* kb = K + kbase + (size_t)(k0 + krow) * D_ + kc;
#pragma unroll
      for (int j = 0; j < 8; j++)
        *(bf16x8*)&KV[krow * 264 + j * 32 + kc] = *(const bf16x8*)(kb + j * 32);
    }
    __syncthreads();

    // Q K^T
    f32x4 sc[4];
#pragma unroll
    for (int nt = 0; nt < 4; nt++) sc[nt] = f32x4{0.f, 0.f, 0.f, 0.f};
#pragma unroll
    for (int nt = 0; nt < 4; nt++)
#pragma unroll
      for (int kf = 0; kf < 8; kf++) {
        bf16x8 bb = *(const bf16x8*)&KV[(nt * 16 + lr) * 264 + kf * 32 + lq * 8];
        sc[nt] = __builtin_amdgcn_mfma_f32_16x16x32_bf16(qf[kf], bb, sc[nt], 0, 0, 0);
      }

    // softcap 50*tanh(s*SCALING/50) (+ causal mask on diagonal tile)
    float cap[4][4];
#pragma unroll
    for (int nt = 0; nt < 4; nt++)
#pragma unroll
      for (int r = 0; r < 4; r++) {
        float x = sc[nt][r] * (float)(0.0625 / 50.0);
        float e = __expf(2.f * x);
        cap[nt][r] = 50.f * (1.f - 2.f / (e + 1.f));
      }
    if (diag) {
#pragma unroll
      for (int nt = 0; nt < 4; nt++) {
        int key = k0 + nt * 16 + lr;
#pragma unroll
        for (int r = 0; r < 4; r++) {
          int qrow = q0 + 16 * w + lq * 4 + r;
          if (key > qrow) cap[nt][r] = -1e9f;
        }
      }
    }
    // online softmax (per-wave private rows)
    float mt[4], psum[4], alpha[4];
#pragma unroll
    for (int r = 0; r < 4; r++)
      mt[r] = fmaxf(fmaxf(cap[0][r], cap[1][r]), fmaxf(cap[2][r], cap[3][r]));
#pragma unroll
    for (int off = 1; off <= 8; off <<= 1)
#pragma unroll
      for (int r = 0; r < 4; r++) mt[r] = fmaxf(mt[r], __shfl_xor(mt[r], off, 64));
#pragma unroll
    for (int r = 0; r < 4; r++) {
      float mn = fmaxf(m_i[r], mt[r]);
      alpha[r] = __expf(m_i[r] - mn);
      m_i[r] = mn;
      psum[r] = 0.f;
    }
#pragma unroll
    for (int nt = 0; nt < 4; nt++)
#pragma unroll
      for (int r = 0; r < 4; r++) {
        float p = __expf(cap[nt][r] - m_i[r]);
        cap[nt][r] = p;
        psum[r] += p;
      }
#pragma unroll
    for (int off = 1; off <= 8; off <<= 1)
#pragma unroll
      for (int r = 0; r < 4; r++) psum[r] += __shfl_xor(psum[r], off, 64);
#pragma unroll
    for (int r = 0; r < 4; r++) l_i[r] = l_i[r] * alpha[r] + psum[r];
#pragma unroll
    for (int dt = 0; dt < 16; dt++)
#pragma unroll
      for (int r = 0; r < 4; r++) o[dt][r] *= alpha[r];
    // P (C-layout) -> LDS -> A-layout
#pragma unroll
    for (int nt = 0; nt < 4; nt++)
#pragma unroll
      for (int r = 0; r < 4; r++)
        Ps[(16 * w + lq * 4 + r) * 72 + nt * 16 + lr] = f2bf(cap[nt][r]);

    __syncthreads();  // all K reads done before Vt overwrites union

    // stage Vt tile (256 d x 64 keys) -> KV as [256][72]
    {
      int vc = (t & 3) * 16;
#pragma unroll
      for (int p = 0; p < 4; p++) {
        int dd = p * 64 + (t >> 2);
        const short* vb = Vt + vbase + (size_t)dd * L_ + k0 + vc;
        *(bf16x8*)&KV[dd * 72 + vc] = *(const bf16x8*)vb;
        *(bf16x8*)&KV[dd * 72 + vc + 8] = *(const bf16x8*)(vb + 8);
      }
    }
    __syncthreads();

    // P * V
    bf16x8 pf0 = *(const bf16x8*)&Ps[(16 * w + lr) * 72 + lq * 8];
    bf16x8 pf1 = *(const bf16x8*)&Ps[(16 * w + lr) * 72 + 32 + lq * 8];
#pragma unroll
    for (int dt = 0; dt < 16; dt++) {
      bf16x8 v0 = *(const bf16x8*)&KV[(dt * 16 + lr) * 72 + lq * 8];
      bf16x8 v1 = *(const bf16x8*)&KV[(dt * 16 + lr) * 72 + 32 + lq * 8];
      o[dt] = __builtin_amdgcn_mfma_f32_16x16x32_bf16(pf0, v0, o[dt], 0, 0, 0);
      o[dt] = __builtin_amdgcn_mfma_f32_16x16x32_bf16(pf1, v1, o[dt], 0, 0, 0);
    }
    __syncthreads();  // Vt reads done before next K stage
  }

  float inv[4];
#pragma unroll
  for (int r = 0; r < 4; r++) inv[r] = 1.f / l_i[r];
#pragma unroll
  for (int dt = 0; dt < 16; dt++)
#pragma unroll
    for (int r = 0; r < 4; r++) {
      size_t row = (size_t)b * S_ + q0 + 16 * w + lq * 4 + r;
      attn_out[row * (HQ_ * D_) + h * D_ + dt * 16 + lr] = f2bf(o[dt][r] * inv[r]);
    }
}

extern "C" void kernel_launch(void* const* d_in, const int* in_sizes, int n_in, void* d_out,
                              int out_size, void* d_ws, size_t ws_size, hipStream_t stream) {
  (void)in_sizes; (void)n_in; (void)out_size; (void)ws_size;
  const float* hidden = (const float*)d_in[0];
  const float* encoder = (const float*)d_in[1];
  const float* cosp = (const float*)d_in[2];
  const float* sinp = (const float*)d_in[3];
  // d_in[4] = merged_attention_mask: deterministic causal+zeros, computed analytically
  const float* Wq = (const float*)d_in[5];
  const float* Wk = (const float*)d_in[6];
  const float* Wv = (const float*)d_in[7];
  const float* Wo = (const float*)d_in[8];
  const float* qnw = (const float*)d_in[9];
  const float* knw = (const float*)d_in[10];

  short* ws = (short*)d_ws;
  short* hs_bf = ws;                       // 8.39M el  (reused later as attn_b)
  short* enc_bf = ws + 8388608;            // 8.39M el  (reused later as Qb)
  short* wqkv_bf = ws + 16777216;          // 8.39M el  [Wq;Wk;Wv] rows x K
  short* wo_bf = ws + 25165824;            // 4.19M el
  short* qkv_self = ws + 29360128;         // 16.78M el (4096 x 4096: q|k|v)
  short* kv_cross = ws + 46137344;         // 8.39M el  (4096 x 2048: k|v)
  short* Kb = ws + 54525952;               // 8.39M el  (B,HKV,L,D)
  short* Vtb = ws + 62914560;              // 8.39M el  (B,HKV,D,L)
  short* attn_b = hs_bf;                   // alias: hs_bf dead after GEMM1
  short* Qb = enc_bf;                      // alias: enc_bf dead after GEMM2

  cvt_f32_bf16<<<8192, 256, 0, stream>>>(hidden, hs_bf, 8388608);
  cvt_f32_bf16<<<8192, 256, 0, stream>>>(encoder, enc_bf, 8388608);
  cvt_f32_bf16<<<4096, 256, 0, stream>>>(Wq, wqkv_bf, 4194304);
  cvt_f32_bf16<<<2048, 256, 0, stream>>>(Wk, wqkv_bf + 4194304, 2097152);
  cvt_f32_bf16<<<2048, 256, 0, stream>>>(Wv, wqkv_bf + 6291456, 2097152);
  cvt_f32_bf16<<<4096, 256, 0, stream>>>(Wo, wo_bf, 4194304);

  gemm_bt<1><<<dim3(32, 32), 256, 0, stream>>>(hs_bf, wqkv_bf, qkv_self, 4096, 4096, 2048);
  gemm_bt<1><<<dim3(16, 32), 256, 0, stream>>>(enc_bf, wqkv_bf + (size_t)2048 * 2048, kv_cross,
                                               4096, 2048, 2048);

  norm_rope<<<32768, 256, 0, stream>>>(qkv_self, 4096, 0, 8, Qb, 2048, 0, 1, qnw, cosp, sinp);
  norm_rope<<<16384, 256, 0, stream>>>(qkv_self, 4096, 2048, 4, Kb, 4096, 0, 1, knw, cosp, sinp);
  norm_rope<<<16384, 256, 0, stream>>>(kv_cross, 2048, 0, 4, Kb, 4096, 2048, 0, knw, cosp, sinp);

  v_transpose<<<2048, 256, 0, stream>>>(qkv_self, kv_cross, Vtb);

  flash_attn<<<512, 256, 0, stream>>>(Qb, Kb, Vtb, attn_b);

  gemm_bt<0><<<dim3(16, 32), 256, 0, stream>>>(attn_b, wo_bf, d_out, 4096, 2048, 2048);
}

// Round 2
// 714.196 us; speedup vs baseline: 1.1632x; 1.1632x over previous
//
#include <hip/hip_runtime.h>
#include <cstdint>

typedef __attribute__((ext_vector_type(8))) short bf16x8;
typedef __attribute__((ext_vector_type(4))) float f32x4;

#define B_ 2
#define S_ 2048
#define ENC_ 2048
#define HID_ 2048
#define HQ_ 8
#define HKV_ 4
#define D_ 256
#define L_ 4096

__device__ __forceinline__ short f2bf(float f) {
  uint32_t u = __builtin_bit_cast(uint32_t, f);
  u = (u + 0x7fffu + ((u >> 16) & 1u)) >> 16;
  return (short)u;
}
__device__ __forceinline__ float bf2f(short s) {
  uint32_t u = ((uint32_t)(uint16_t)s) << 16;
  return __builtin_bit_cast(float, u);
}

// global -> LDS direct copy, 16B per lane. LDS dest = wave-uniform base + lane*16.
__device__ __forceinline__ void llds16(const void* g, void* s) {
  __builtin_amdgcn_global_load_lds(
      (const __attribute__((address_space(1))) void*)(__builtin_bit_cast(uintptr_t, g)),
      (__attribute__((address_space(3))) void*)(uint32_t)(__builtin_bit_cast(uintptr_t, s)),
      16, 0, 0);
}

// ---------------- fp32 -> bf16 convert ----------------
__global__ __launch_bounds__(256) void cvt_f32_bf16(const float* __restrict__ in,
                                                    short* __restrict__ out, int n) {
  int i = (blockIdx.x * 256 + threadIdx.x) * 4;
  if (i >= n) return;
  float4 v = *(const float4*)(in + i);
  short4 r;
  r.x = f2bf(v.x); r.y = f2bf(v.y); r.z = f2bf(v.z); r.w = f2bf(v.w);
  *(short4*)(out + i) = r;
}

// ---------------- GEMM C = A * B^T (both K-major), 128x128 tile, BK=32 ----------------
template <int BF16OUT>
__global__ __launch_bounds__(256, 2)
void gemm_bt(const short* __restrict__ A, const short* __restrict__ Bw,
             void* __restrict__ Cout, int M, int N, int K) {
  __shared__ __align__(16) short As[128 * 32];
  __shared__ __align__(16) short Bs[128 * 32];
  const int t = threadIdx.x;
  const int w = t >> 6;
  const int l = t & 63;
  const int lr = l & 15;
  const int lq = l >> 4;
  const int bm = blockIdx.y * 128;
  const int bn = blockIdx.x * 128;
  const int wm = (w & 1) * 64;
  const int wn = (w >> 1) * 64;

  f32x4 acc[4][4];
#pragma unroll
  for (int i = 0; i < 4; i++)
#pragma unroll
    for (int j = 0; j < 4; j++) acc[i][j] = f32x4{0.f, 0.f, 0.f, 0.f};

  const int srow = 32 * w + (l >> 2);  // staging row (issue 0); +16 for issue 1
  const int scol = (l & 3) * 8;
  const short* gA = A + (size_t)(bm + srow) * K + scol;
  const short* gB = Bw + (size_t)(bn + srow) * K + scol;
  short* sA = &As[srow * 32 + scol];
  short* sB = &Bs[srow * 32 + scol];

  for (int k0 = 0; k0 < K; k0 += 32) {
    llds16(gA + k0, sA);
    llds16(gA + k0 + (size_t)16 * K, sA + 16 * 32);
    llds16(gB + k0, sB);
    llds16(gB + k0 + (size_t)16 * K, sB + 16 * 32);
    __syncthreads();
    bf16x8 af[4], bfr[4];
#pragma unroll
    for (int mi = 0; mi < 4; mi++)
      af[mi] = *(const bf16x8*)&As[(wm + 16 * mi + lr) * 32 + lq * 8];
#pragma unroll
    for (int ni = 0; ni < 4; ni++)
      bfr[ni] = *(const bf16x8*)&Bs[(wn + 16 * ni + lr) * 32 + lq * 8];
    __syncthreads();
#pragma unroll
    for (int mi = 0; mi < 4; mi++)
#pragma unroll
      for (int ni = 0; ni < 4; ni++)
        acc[mi][ni] =
            __builtin_amdgcn_mfma_f32_16x16x32_bf16(af[mi], bfr[ni], acc[mi][ni], 0, 0, 0);
  }

#pragma unroll
  for (int mi = 0; mi < 4; mi++)
#pragma unroll
    for (int ni = 0; ni < 4; ni++)
#pragma unroll
      for (int r = 0; r < 4; r++) {
        int row = bm + wm + 16 * mi + lq * 4 + r;  // C layout: row=(l>>4)*4+reg
        int col = bn + wn + 16 * ni + lr;          //           col=l&15
        float v = acc[mi][ni][r];
        if (BF16OUT)
          ((short*)Cout)[(size_t)row * N + col] = f2bf(v);
        else
          ((float*)Cout)[(size_t)row * N + col] = v;
      }
}

// ---------------- RMSNorm (+ optional RoPE) + head-major scatter ----------------
__global__ __launch_bounds__(256)
void norm_rope(const short* __restrict__ src, int src_ld, int col0, int H,
               short* __restrict__ dst, int dstL, int pos_off, int do_rope,
               const float* __restrict__ wn, const float* __restrict__ cosp,
               const float* __restrict__ sinp) {
  __shared__ float sh[256];
  __shared__ float red[4];
  int bid = blockIdx.x;
  int s = bid & (S_ - 1);
  int h = (bid >> 11) % H;
  int b = (bid >> 11) / H;
  int d = threadIdx.x;
  int w = d >> 6, l = d & 63;
  float x = bf2f(src[(size_t)(b * S_ + s) * src_ld + col0 + h * D_ + d]);
  float ss = x * x;
#pragma unroll
  for (int off = 32; off; off >>= 1) ss += __shfl_xor(ss, off, 64);
  if (l == 0) red[w] = ss;
  __syncthreads();
  float tot = red[0] + red[1] + red[2] + red[3];
  float y = x * rsqrtf(tot * (1.0f / D_) + 1e-6f) * (1.0f + wn[d]);
  float outv = y;
  if (do_rope) {
    sh[d] = y;
    __syncthreads();
    float c = cosp[s * D_ + d];
    float sn = sinp[s * D_ + d];
    outv = (d < 128) ? (y * c - sh[d + 128] * sn) : (y * c + sh[d - 128] * sn);
  }
  dst[((size_t)(b * H + h) * dstL + pos_off + s) * D_ + d] = f2bf(outv);
}

// ---------------- V transpose: (token, d) -> Vt[b][h][d][l] ----------------
__global__ __launch_bounds__(256)
void v_transpose(const short* __restrict__ qkv_self, const short* __restrict__ kv_cross,
                 short* __restrict__ Vt) {
  __shared__ __align__(16) short tile[64][72];
  int bid = blockIdx.x;  // b(2) h(4) lt(64) dt(4)
  int dt = bid & 3;
  int lt = (bid >> 2) & 63;
  int h = (bid >> 8) & 3;
  int b = bid >> 10;
  int t = threadIdx.x;
  int rl = t >> 2;
  int cc = (t & 3) * 16;
  int l = lt * 64 + rl;
  const short* src;
  if (lt < 32)
    src = qkv_self + (size_t)(b * S_ + l) * 4096 + 3072 + h * D_ + dt * 64 + cc;
  else
    src = kv_cross + (size_t)(b * ENC_ + (l - S_)) * 2048 + 1024 + h * D_ + dt * 64 + cc;
  *(bf16x8*)&tile[rl][cc] = *(const bf16x8*)src;
  *(bf16x8*)&tile[rl][cc + 8] = *(const bf16x8*)(src + 8);
  __syncthreads();
  int dl = t >> 2;
  int lc = (t & 3) * 16;
  bf16x8 v0, v1;
#pragma unroll
  for (int j = 0; j < 8; j++) {
    v0[j] = tile[lc + j][dl];
    v1[j] = tile[lc + 8 + j][dl];
  }
  short* dstp = Vt + ((size_t)(b * HKV_ + h) * D_ + dt * 64 + dl) * (size_t)L_ + lt * 64 + lc;
  *(bf16x8*)dstp = v0;
  *(bf16x8*)(dstp + 8) = v1;
}

// ---------------- Flash attention with tanh softcap, k-split x2 ----------------
// Each block handles one (b,h,qt,parity): the parity class of the valid
// 64-key k-tile list (self j<=qt, cross j in [32,64), k0=j*64 uniformly).
// Writes l-normalized O (bf16) + per-row (m,l) stats; combine2 merges.
__global__ __launch_bounds__(256, 2)
void flash_attn(const short* __restrict__ Q, const short* __restrict__ K,
                const short* __restrict__ Vt, short* __restrict__ o_split,
                float2* __restrict__ stats) {
  __shared__ __align__(16) short KV[256 * 72];  // union: K view [64][264], Vt view [256][72]
  __shared__ __align__(16) short Ps[64 * 72];
  int t = threadIdx.x, w = t >> 6, l = t & 63;
  int lr = l & 15, lq = l >> 4;
  int bid = blockIdx.x;
  // bid = qtord*32 + (b*16 + h*2 + p); qtord 0 = heaviest (qt=31) dispatched first
  int qt = 31 - (bid >> 5);
  int rest = bid & 31;
  int p = rest & 1;
  int h = (rest >> 1) & 7;
  int b = rest >> 4;
  int hk = h >> 1;  // GQA repeat=2
  int q0 = qt * 64;

  bf16x8 qf[8];  // wave's 16 q-rows, full D=256, A-fragment layout, kept in regs
  {
    const short* qb = Q + ((size_t)(b * HQ_ + h) * S_ + q0 + 16 * w + lr) * D_ + lq * 8;
#pragma unroll
    for (int kf = 0; kf < 8; kf++) qf[kf] = *(const bf16x8*)(qb + kf * 32);
  }
  f32x4 o[16];
#pragma unroll
  for (int i = 0; i < 16; i++) o[i] = f32x4{0.f, 0.f, 0.f, 0.f};
  float m_i[4] = {-1e9f, -1e9f, -1e9f, -1e9f};
  float l_i[4] = {0.f, 0.f, 0.f, 0.f};

  const size_t kbase = (size_t)(b * HKV_ + hk) * L_ * D_;
  const size_t vbase = (size_t)(b * HKV_ + hk) * (size_t)D_ * L_;

  // parity p takes j in {p, p+2, ...}: nself self tiles, then 16 cross tiles
  int nself = (qt >= p) ? (((qt - p) >> 1) + 1) : 0;
  int niter = nself + 16;
  for (int it = 0; it < niter; ++it) {
    int j = (it < nself) ? (p + 2 * it) : (32 + p + 2 * (it - nself));
    int k0 = j * 64;
    bool diag = (j == qt);

    // stage K tile (64 keys x 256 d) -> KV as [64][264]
    {
      int krow = t >> 2;
      int kc = (t & 3) * 8;
      const short* kb = K + kbase + (size_t)(k0 + krow) * D_ + kc;
#pragma unroll
      for (int jj = 0; jj < 8; jj++)
        *(bf16x8*)&KV[krow * 264 + jj * 32 + kc] = *(const bf16x8*)(kb + jj * 32);
    }
    __syncthreads();

    // Q K^T
    f32x4 sc[4];
#pragma unroll
    for (int nt = 0; nt < 4; nt++) sc[nt] = f32x4{0.f, 0.f, 0.f, 0.f};
#pragma unroll
    for (int nt = 0; nt < 4; nt++)
#pragma unroll
      for (int kf = 0; kf < 8; kf++) {
        bf16x8 bb = *(const bf16x8*)&KV[(nt * 16 + lr) * 264 + kf * 32 + lq * 8];
        sc[nt] = __builtin_amdgcn_mfma_f32_16x16x32_bf16(qf[kf], bb, sc[nt], 0, 0, 0);
      }

    // softcap 50*tanh(s*SCALING/50) (+ causal mask on diagonal tile)
    float cap[4][4];
#pragma unroll
    for (int nt = 0; nt < 4; nt++)
#pragma unroll
      for (int r = 0; r < 4; r++) {
        float x = sc[nt][r] * (float)(0.0625 / 50.0);
        float e = __expf(2.f * x);
        cap[nt][r] = 50.f * (1.f - 2.f / (e + 1.f));
      }
    if (diag) {
#pragma unroll
      for (int nt = 0; nt < 4; nt++) {
        int key = k0 + nt * 16 + lr;
#pragma unroll
        for (int r = 0; r < 4; r++) {
          int qrow = q0 + 16 * w + lq * 4 + r;
          if (key > qrow) cap[nt][r] = -1e9f;
        }
      }
    }
    // online softmax (per-wave private rows)
    float mt[4], psum[4], alpha[4];
#pragma unroll
    for (int r = 0; r < 4; r++)
      mt[r] = fmaxf(fmaxf(cap[0][r], cap[1][r]), fmaxf(cap[2][r], cap[3][r]));
#pragma unroll
    for (int off = 1; off <= 8; off <<= 1)
#pragma unroll
      for (int r = 0; r < 4; r++) mt[r] = fmaxf(mt[r], __shfl_xor(mt[r], off, 64));
#pragma unroll
    for (int r = 0; r < 4; r++) {
      float mn = fmaxf(m_i[r], mt[r]);
      alpha[r] = __expf(m_i[r] - mn);
      m_i[r] = mn;
      psum[r] = 0.f;
    }
#pragma unroll
    for (int nt = 0; nt < 4; nt++)
#pragma unroll
      for (int r = 0; r < 4; r++) {
        float pp = __expf(cap[nt][r] - m_i[r]);
        cap[nt][r] = pp;
        psum[r] += pp;
      }
#pragma unroll
    for (int off = 1; off <= 8; off <<= 1)
#pragma unroll
      for (int r = 0; r < 4; r++) psum[r] += __shfl_xor(psum[r], off, 64);
#pragma unroll
    for (int r = 0; r < 4; r++) l_i[r] = l_i[r] * alpha[r] + psum[r];
#pragma unroll
    for (int dt = 0; dt < 16; dt++)
#pragma unroll
      for (int r = 0; r < 4; r++) o[dt][r] *= alpha[r];
    // P (C-layout) -> LDS -> A-layout
#pragma unroll
    for (int nt = 0; nt < 4; nt++)
#pragma unroll
      for (int r = 0; r < 4; r++)
        Ps[(16 * w + lq * 4 + r) * 72 + nt * 16 + lr] = f2bf(cap[nt][r]);

    __syncthreads();  // all K reads done before Vt overwrites union

    // stage Vt tile (256 d x 64 keys) -> KV as [256][72]
    {
      int vc = (t & 3) * 16;
#pragma unroll
      for (int pp = 0; pp < 4; pp++) {
        int dd = pp * 64 + (t >> 2);
        const short* vb = Vt + vbase + (size_t)dd * L_ + k0 + vc;
        *(bf16x8*)&KV[dd * 72 + vc] = *(const bf16x8*)vb;
        *(bf16x8*)&KV[dd * 72 + vc + 8] = *(const bf16x8*)(vb + 8);
      }
    }
    __syncthreads();

    // P * V
    bf16x8 pf0 = *(const bf16x8*)&Ps[(16 * w + lr) * 72 + lq * 8];
    bf16x8 pf1 = *(const bf16x8*)&Ps[(16 * w + lr) * 72 + 32 + lq * 8];
#pragma unroll
    for (int dt = 0; dt < 16; dt++) {
      bf16x8 v0 = *(const bf16x8*)&KV[(dt * 16 + lr) * 72 + lq * 8];
      bf16x8 v1 = *(const bf16x8*)&KV[(dt * 16 + lr) * 72 + 32 + lq * 8];
      o[dt] = __builtin_amdgcn_mfma_f32_16x16x32_bf16(pf0, v0, o[dt], 0, 0, 0);
      o[dt] = __builtin_amdgcn_mfma_f32_16x16x32_bf16(pf1, v1, o[dt], 0, 0, 0);
    }
    __syncthreads();  // Vt reads done before next K stage
  }

  float inv[4];
#pragma unroll
  for (int r = 0; r < 4; r++) inv[r] = 1.f / l_i[r];
  short* ob = o_split + (size_t)p * (B_ * S_ * HQ_ * D_);
#pragma unroll
  for (int dt = 0; dt < 16; dt++)
#pragma unroll
    for (int r = 0; r < 4; r++) {
      size_t row = (size_t)b * S_ + q0 + 16 * w + lq * 4 + r;
      ob[row * (HQ_ * D_) + h * D_ + dt * 16 + lr] = f2bf(o[dt][r] * inv[r]);
    }
  if (lr == 0) {
#pragma unroll
    for (int r = 0; r < 4; r++) {
      int row = q0 + 16 * w + lq * 4 + r;
      stats[(((size_t)p * B_ + b) * HQ_ + h) * S_ + row] = float2{m_i[r], l_i[r]};
    }
  }
}

// ---------------- combine the two k-split partitions ----------------
__global__ __launch_bounds__(256)
void combine2(const short* __restrict__ o_split, const float2* __restrict__ stats,
              short* __restrict__ out) {
  int tid = blockIdx.x * 256 + threadIdx.x;
  int flat = tid * 4;  // element in [B*S*HQ*D)
  int h = (flat >> 8) & 7;
  int s = (flat >> 11) & 2047;
  int b = flat >> 22;
  float2 st0 = stats[(((size_t)0 * B_ + b) * HQ_ + h) * S_ + s];
  float2 st1 = stats[(((size_t)1 * B_ + b) * HQ_ + h) * S_ + s];
  float m = fmaxf(st0.x, st1.x);
  float w0 = __expf(st0.x - m) * st0.y;
  float w1 = __expf(st1.x - m) * st1.y;
  float inv = 1.f / (w0 + w1);
  w0 *= inv;
  w1 *= inv;
  short4 a = *(const short4*)(o_split + (size_t)flat);
  short4 c = *(const short4*)(o_split + (size_t)(B_ * S_ * HQ_ * D_) + flat);
  short4 r;
  r.x = f2bf(w0 * bf2f(a.x) + w1 * bf2f(c.x));
  r.y = f2bf(w0 * bf2f(a.y) + w1 * bf2f(c.y));
  r.z = f2bf(w0 * bf2f(a.z) + w1 * bf2f(c.z));
  r.w = f2bf(w0 * bf2f(a.w) + w1 * bf2f(c.w));
  *(short4*)(out + flat) = r;
}

extern "C" void kernel_launch(void* const* d_in, const int* in_sizes, int n_in, void* d_out,
                              int out_size, void* d_ws, size_t ws_size, hipStream_t stream) {
  (void)in_sizes; (void)n_in; (void)out_size; (void)ws_size;
  const float* hidden = (const float*)d_in[0];
  const float* encoder = (const float*)d_in[1];
  const float* cosp = (const float*)d_in[2];
  const float* sinp = (const float*)d_in[3];
  // d_in[4] = merged_attention_mask: deterministic causal+zeros, computed analytically
  const float* Wq = (const float*)d_in[5];
  const float* Wk = (const float*)d_in[6];
  const float* Wv = (const float*)d_in[7];
  const float* Wo = (const float*)d_in[8];
  const float* qnw = (const float*)d_in[9];
  const float* knw = (const float*)d_in[10];

  short* ws = (short*)d_ws;
  short* hs_bf = ws;                       // 8.39M el  (reused later as attn_b)
  short* enc_bf = ws + 8388608;            // 8.39M el  (reused later as Qb)
  short* wqkv_bf = ws + 16777216;          // 8.39M el  [Wq;Wk;Wv] rows x K
  short* wo_bf = ws + 25165824;            // 4.19M el
  short* qkv_self = ws + 29360128;         // 16.78M el (4096 x 4096: q|k|v)
  short* kv_cross = ws + 46137344;         // 8.39M el  (4096 x 2048: k|v)
  short* Kb = ws + 54525952;               // 8.39M el  (B,HKV,L,D)
  short* Vtb = ws + 62914560;              // 8.39M el  (B,HKV,D,L)
  short* attn_b = hs_bf;                   // alias: hs_bf dead after GEMM1
  short* Qb = enc_bf;                      // alias: enc_bf dead after GEMM2
  short* o_split = qkv_self;               // alias: dead after v_transpose (2x 8.39M el)
  float2* stats = (float2*)kv_cross;       // alias: dead after norm/v_transpose (512KB)

  cvt_f32_bf16<<<8192, 256, 0, stream>>>(hidden, hs_bf, 8388608);
  cvt_f32_bf16<<<8192, 256, 0, stream>>>(encoder, enc_bf, 8388608);
  cvt_f32_bf16<<<4096, 256, 0, stream>>>(Wq, wqkv_bf, 4194304);
  cvt_f32_bf16<<<2048, 256, 0, stream>>>(Wk, wqkv_bf + 4194304, 2097152);
  cvt_f32_bf16<<<2048, 256, 0, stream>>>(Wv, wqkv_bf + 6291456, 2097152);
  cvt_f32_bf16<<<4096, 256, 0, stream>>>(Wo, wo_bf, 4194304);

  gemm_bt<1><<<dim3(32, 32), 256, 0, stream>>>(hs_bf, wqkv_bf, qkv_self, 4096, 4096, 2048);
  gemm_bt<1><<<dim3(16, 32), 256, 0, stream>>>(enc_bf, wqkv_bf + (size_t)2048 * 2048, kv_cross,
                                               4096, 2048, 2048);

  norm_rope<<<32768, 256, 0, stream>>>(qkv_self, 4096, 0, 8, Qb, 2048, 0, 1, qnw, cosp, sinp);
  norm_rope<<<16384, 256, 0, stream>>>(qkv_self, 4096, 2048, 4, Kb, 4096, 0, 1, knw, cosp, sinp);
  norm_rope<<<16384, 256, 0, stream>>>(kv_cross, 2048, 0, 4, Kb, 4096, 2048, 0, knw, cosp, sinp);

  v_transpose<<<2048, 256, 0, stream>>>(qkv_self, kv_cross, Vtb);

  flash_attn<<<1024, 256, 0, stream>>>(Qb, Kb, Vtb, o_split, stats);
  combine2<<<8192, 256, 0, stream>>>(o_split, stats, attn_b);

  gemm_bt<0><<<dim3(16, 32), 256, 0, stream>>>(attn_b, wo_bf, d_out, 4096, 2048, 2048);
}